// Round 1
// baseline (1130.153 us; speedup 1.0000x reference)
//
#include <hip/hip_runtime.h>

typedef unsigned short u16;
typedef unsigned int u32;
typedef __attribute__((ext_vector_type(4))) float f32x4;
typedef __attribute__((ext_vector_type(8))) short short8;
typedef __attribute__((ext_vector_type(4))) u16 u16x4;
typedef __attribute__((ext_vector_type(8))) u16 u16x8;

#define N_TOK 16384
#define C_DIM 768
#define I_DIM 1536
#define N_EXP 16
#define TM 256          // row-tile (padding granularity)
#define BK 64
#define MAXT 208        // worst-case tiles: <=144 routed + 64 shared
#define PASS_T 104      // tiles per pass (two passes)

// ctrl region int offsets (first 1MB of ws)
#define CI_COUNTS 0
#define CI_STARTS 32
#define CI_NTILES 64
#define CI_TILE_E 128        // [208]
#define CI_ESLOT 2048        // [N][2] packed (e<<24)|slot
#define CI_TOKW 36864        // [N][2] float weights
#define CI_PERM 102400       // [53248] padded row -> token (-1 = padding)
#define CI_RW 155648         // [53248] float per-row combine weight

// ws layout (bytes) — total 228,327,424 (budget 262,144,000)
#define XB_OFF  1048576u             // bf16 x: 16384*768*2 = 25,165,824
#define WGU_OFF 26214400u            // bf16 [17][2I][C] g/u 16-interleaved, swizzled: 80,216,064
#define WDP_OFF 106430464u           // bf16 [17][C][I] swizzled:    40,108,032
#define ACT_OFF 146538496u           // bf16 act half: 26624*1536*2 = 81,788,928

// raw barrier (no compiler-forced vmcnt(0) drain) + counted vmem waits
#define BAR() asm volatile("s_barrier" ::: "memory")
#define WAITVM(N) asm volatile("s_waitcnt vmcnt(" #N ")" ::: "memory")

__device__ __forceinline__ u16 f2bf(float f) {
  u32 x = __float_as_uint(f);
  return (u16)((x + 0x7FFFu + ((x >> 16) & 1u)) >> 16);  // RNE
}
__device__ __forceinline__ float bf2f(u16 h) {
  return __uint_as_float(((u32)h) << 16);
}
__device__ __forceinline__ void dma16(const void* g, void* l) {
  __builtin_amdgcn_global_load_lds(
      (const __attribute__((address_space(1))) unsigned int*)g,
      (__attribute__((address_space(3))) unsigned int*)l, 16, 0, 0);
}

// ---------------- weight convert: fp32 [K][N] -> bf16 [N][K], chunk-XOR swizzle baked.
// wgu: per expert a single [2I][C] matrix whose rows interleave g/u at 16-col
// granularity: combined row ng -> block b=ng>>5, gu=(ng>>4)&1, src col b*16+(ng&15).
// So a 16-wide MFMA B-fragment is pure g or pure u, and fragments n and n+1 of a
// wave cover the SAME output cols (g then u) -> silu pairing is wave-local.
__global__ void convert_kernel(const float* __restrict__ wg, const float* __restrict__ wu,
                               const float* __restrict__ wd, const float* __restrict__ swg,
                               const float* __restrict__ swu, const float* __restrict__ swd,
                               u16* __restrict__ wgu, u16* __restrict__ wdp) {
  int bid = blockIdx.x;
  int tid = threadIdx.x, lane = tid & 63, wv = tid >> 6;
  int lsub = lane >> 3, lchk = lane & 7;
  if (bid < 17 * 96) {                     // combined g/u part: 17 experts x 3072 rows
    int e = bid / 96, nb = bid % 96;
    int ng = nb * 32 + wv * 8 + lsub;      // combined dst row 0..3071
    int gu = (ng >> 4) & 1;
    int scol = ((ng >> 5) << 4) | (ng & 15);
    const float* src = (e < N_EXP) ? ((gu ? wu : wg) + (size_t)e * C_DIM * I_DIM)
                                   : (gu ? swu : swg);
    u16* drow = wgu + ((size_t)e * (2 * I_DIM) + ng) * C_DIM;
    int c = lchk ^ (ng & 7);               // source chunk stored at position lchk
    const float* s0 = src + scol;
    for (int k0 = 0; k0 < C_DIM; k0 += 64) {
      u16x8 o;
#pragma unroll
      for (int j = 0; j < 8; j++) o[j] = f2bf(s0[(size_t)(k0 + c * 8 + j) * I_DIM]);
      *(u16x8*)&drow[k0 + lchk * 8] = o;
    }
  } else {                                 // wd part: [I][C] -> [C][I]
    int b2 = bid - 17 * 96;
    int e = b2 / 24, nb = b2 % 24;
    const float* src = (e < N_EXP) ? (wd + (size_t)e * I_DIM * C_DIM) : swd;
    u16* dst = wdp + (size_t)e * (I_DIM * C_DIM);
    int ng = nb * 32 + wv * 8 + lsub;
    int c = lchk ^ (ng & 7);
    const float* s0 = src + ng;
    u16* drow = dst + (size_t)ng * I_DIM;
    for (int k0 = 0; k0 < I_DIM; k0 += 64) {
      u16x8 o;
#pragma unroll
      for (int j = 0; j < 8; j++) o[j] = f2bf(s0[(size_t)(k0 + c * 8 + j) * C_DIM]);
      *(u16x8*)&drow[k0 + lchk * 8] = o;
    }
  }
}

// ---------------- router: fp32 logits, top-2, weights, counts; also casts x->bf16
__global__ void router_kernel(const float* __restrict__ x, const float* __restrict__ wgate,
                              const float* __restrict__ ebias, int* __restrict__ ctrl,
                              u16* __restrict__ xb) {
  __shared__ float xs[16 * 772];
  __shared__ float wgsT[16 * 772];      // transposed [e][c]
  __shared__ float lg[16 * 16];
  int tid = threadIdx.x;
  int tok0 = blockIdx.x * 16;
  const float4* xsrc = (const float4*)(x + (size_t)tok0 * C_DIM);
  const float4* wsrc = (const float4*)wgate;
#pragma unroll
  for (int j = 0; j < 12; j++) {
    int q = tid + j * 256;              // float4 unit, 0..3071
    float4 v = xsrc[q];
    int tk = q / 192;
    int c4 = q - tk * 192;
    *(float4*)&xs[tk * 772 + c4 * 4] = v;
    u16x4 o; o.x = f2bf(v.x); o.y = f2bf(v.y); o.z = f2bf(v.z); o.w = f2bf(v.w);
    *(u16x4*)(xb + (size_t)tok0 * C_DIM + (size_t)q * 4) = o;   // fused x->bf16 cast
    float4 w = wsrc[q];
    int c = q >> 2, e0 = (q & 3) * 4;
    wgsT[(e0 + 0) * 772 + c] = w.x;
    wgsT[(e0 + 1) * 772 + c] = w.y;
    wgsT[(e0 + 2) * 772 + c] = w.z;
    wgsT[(e0 + 3) * 772 + c] = w.w;
  }
  __syncthreads();
  int tk = tid >> 4, e = tid & 15;
  float acc = ebias[e];
  const float4* xr = (const float4*)&xs[tk * 772];
  const float4* wr = (const float4*)&wgsT[e * 772];
#pragma unroll 4
  for (int c4 = 0; c4 < 192; c4++) {
    float4 xv = xr[c4], wv = wr[c4];
    acc = fmaf(xv.x, wv.x, fmaf(xv.y, wv.y, fmaf(xv.z, wv.z, fmaf(xv.w, wv.w, acc))));
  }
  lg[tk * 16 + e] = acc;
  __syncthreads();
  if (tid < 16) {
    int n = tok0 + tid;
    float l0 = -1e30f, l1 = -1e30f; int i0 = 0, i1 = 0;
#pragma unroll
    for (int j = 0; j < 16; j++) {
      float l = lg[tid * 16 + j];
      if (l > l0) { l1 = l0; i1 = i0; l0 = l; i0 = j; }
      else if (l > l1) { l1 = l; i1 = j; }
    }
    float e1 = __expf(l1 - l0);
    float inv = 1.f / (1.f + e1);
    int s0 = atomicAdd(&ctrl[CI_COUNTS + i0], 1);
    int s1 = atomicAdd(&ctrl[CI_COUNTS + i1], 1);
    ctrl[CI_ESLOT + 2 * n]     = (i0 << 24) | s0;
    ctrl[CI_ESLOT + 2 * n + 1] = (i1 << 24) | s1;
    float* tw = (float*)(ctrl + CI_TOKW);
    tw[2 * n] = inv; tw[2 * n + 1] = e1 * inv;
  }
}

// ---------------- segment starts (padded to 256) + tile->expert map; shared = expert 16
__global__ void tiles_kernel(int* __restrict__ ctrl) {
  if (threadIdx.x != 0) return;
  int cnt[17];
#pragma unroll
  for (int e = 0; e < 16; e++) cnt[e] = ctrl[CI_COUNTS + e];
  cnt[16] = N_TOK;
  ctrl[CI_COUNTS + 16] = N_TOK;
  int cur = 0, T = 0;
  for (int e = 0; e <= 16; e++) {
    ctrl[CI_STARTS + e] = cur;
    int nt = (cnt[e] + TM - 1) >> 8;
    for (int i = 0; i < nt; i++) ctrl[CI_TILE_E + T++] = e;
    cur += nt << 8;
  }
  ctrl[CI_NTILES] = T;
}

// ---------------- scatter: fill perm[row]->token and per-row combine weight
__global__ void scatter_kernel(int* __restrict__ ctrl) {
  int n = blockIdx.x * 256 + threadIdx.x;
  const float* tw = (const float*)(ctrl + CI_TOKW);
  float* rw = (float*)(ctrl + CI_RW);
#pragma unroll
  for (int k = 0; k < 2; k++) {
    int es = ctrl[CI_ESLOT + 2 * n + k];
    int e = es >> 24;
    int slot = es & 0xFFFFFF;
    int row = ctrl[CI_STARTS + e] + slot;
    ctrl[CI_PERM + row] = n;
    rw[row] = tw[2 * n + k];
  }
  int srow = ctrl[CI_STARTS + 16] + n;     // shared expert row
  ctrl[CI_PERM + srow] = n;
  rw[srow] = 1.0f;
}

// ---------------- GEMM1: 256x256 combined tile, 8 waves, counted-vmcnt pipeline.
// act = silu(x@Wg) * (x@Wu); B cols interleave g/u at 16 so pairing is in-wave.
// Schedule per K-tile t (slot = t&1):
//   ds_read frags(slot) -> 64 MFMA   (compiler lgkm-gates; all reads retired before BAR)
//   BAR();                            // every wave done READING slot
//   stage(t+2 -> slot);               // overwrite only after the barrier above
//   WAITVM(8);                        // oldest 8 (= K-tile t+1) landed; t+2 stays in flight
//   BAR();
__global__ __launch_bounds__(512, 2)
void gemm1_kernel(const u16* __restrict__ xb, const u16* __restrict__ wgu,
                  u16* __restrict__ act, const int* __restrict__ ctrl, int tile0) {
  __shared__ u16 As[2][256 * 64];
  __shared__ u16 Bs[2][256 * 64];
  int tt = tile0 + blockIdx.x;
  if (tt >= ctrl[CI_NTILES]) return;
  int e = ctrl[CI_TILE_E + tt];
  int row0 = tt << 8;                      // global padded row base
  int row0l = blockIdx.x << 8;             // pass-local row base (act index)
  int col0c = blockIdx.y << 8;             // combined col base
  int seg = ctrl[CI_STARTS + e];
  bool sh = (e == N_EXP);
  const u16* W = wgu + (size_t)e * (2 * I_DIM * C_DIM);
  int rlim = sh ? 0x7fffffff : (seg + ctrl[CI_COUNTS + e]);
  const int* perm = ctrl + CI_PERM;
  int tid = threadIdx.x;
  int lane = tid & 63, wv = tid >> 6;
  int lsub = lane >> 3, lchk = lane & 7;
  int co = (lchk ^ lsub) * 8;              // A per-lane swizzled source chunk (elems)
  const u16* aptr[4];
#pragma unroll
  for (int j = 0; j < 4; j++) {
    int r = row0 + wv * 32 + j * 8 + lsub;
    int tok = sh ? (r - seg) : ((r < rlim) ? perm[r] : 0);
    aptr[j] = xb + (size_t)tok * C_DIM + co;
  }
  const u16* bptr = W + (size_t)(col0c + wv * 32 + lsub) * C_DIM + lchk * 8;
  int ldst = (wv * 32 + lsub) * 64 + lchk * 8;   // u16 elems; +j*512 per 8-row group

  f32x4 acc[8][4];
#pragma unroll
  for (int m = 0; m < 8; m++)
#pragma unroll
    for (int n = 0; n < 4; n++) {
      f32x4 z = {0.f, 0.f, 0.f, 0.f};
      acc[m][n] = z;
    }
  int lr = lane & 15, lq = lane >> 4;
  int wr = wv >> 2, wc = wv & 3;           // wave tile: 128 rows x 64 combined cols

  auto stage = [&](int kt, int slot) {
    int kk = kt * BK;
#pragma unroll
    for (int j = 0; j < 4; j++) dma16(aptr[j] + kk, &As[slot][ldst + j * 512]);
#pragma unroll
    for (int j = 0; j < 4; j++)
      dma16(bptr + (size_t)j * (8 * C_DIM) + kk, &Bs[slot][ldst + j * 512]);
  };

  stage(0, 0);
  stage(1, 1);
  WAITVM(8);                               // slot0 landed (slot1's 8 still in flight)
  BAR();
  for (int kt = 0; kt < C_DIM / BK; ++kt) {
    const u16* Ab = As[kt & 1];
    const u16* Bb = Bs[kt & 1];
    __builtin_amdgcn_s_setprio(1);
#pragma unroll
    for (int s = 0; s < 2; ++s) {
      int csh = ((s * 4 + lq) ^ (lr & 7)) * 8;
      short8 bfr[4];
#pragma unroll
      for (int n = 0; n < 4; n++)
        bfr[n] = *(const short8*)&Bb[(wc * 64 + n * 16 + lr) * 64 + csh];
#pragma unroll
      for (int mh = 0; mh < 2; ++mh) {
        short8 afr[4];
#pragma unroll
        for (int mm = 0; mm < 4; mm++)
          afr[mm] = *(const short8*)&Ab[(wr * 128 + mh * 64 + mm * 16 + lr) * 64 + csh];
#pragma unroll
        for (int mm = 0; mm < 4; mm++)
#pragma unroll
          for (int n = 0; n < 4; n++)
            acc[mh * 4 + mm][n] = __builtin_amdgcn_mfma_f32_16x16x32_bf16(
                afr[mm], bfr[n], acc[mh * 4 + mm][n], 0, 0, 0);
      }
    }
    __builtin_amdgcn_s_setprio(0);
    BAR();
    if (kt + 2 < C_DIM / BK) { stage(kt + 2, kt & 1); WAITVM(8); }
    else { WAITVM(0); }
    BAR();
  }
  // epilogue: pair g (n even) with u (n odd), silu, store bf16
  int cb = (blockIdx.y << 7) + wc * 32;    // act col base for this wave
#pragma unroll
  for (int m = 0; m < 8; m++)
#pragma unroll
    for (int np = 0; np < 2; np++)
#pragma unroll
      for (int rg = 0; rg < 4; rg++) {
        float g = acc[m][2 * np][rg];
        float h = acc[m][2 * np + 1][rg];
        float a = g * (1.f / (1.f + __expf(-g))) * h;
        int r_loc = wr * 128 + m * 16 + lq * 4 + rg;
        act[(size_t)(row0l + r_loc) * I_DIM + cb + np * 16 + lr] = f2bf(a);
      }
}

// ---------------- GEMM2: 256x128 tile, 8 waves, same counted-vmcnt pipeline.
// out += rowweight * (act @ Wd), fp32 atomics.
__global__ __launch_bounds__(512, 2)
void gemm2_kernel(const u16* __restrict__ act, const u16* __restrict__ wdp,
                  float* __restrict__ out, const int* __restrict__ ctrl, int tile0) {
  __shared__ u16 As[2][256 * 64];
  __shared__ u16 Bs[2][128 * 64];
  int tt = tile0 + blockIdx.x;
  if (tt >= ctrl[CI_NTILES]) return;
  int e = ctrl[CI_TILE_E + tt];
  int row0 = tt << 8;
  int row0l = blockIdx.x << 8;
  int col0 = blockIdx.y << 7;              // over C
  const u16* D = wdp + (size_t)e * (I_DIM * C_DIM);
  int tid = threadIdx.x;
  int lane = tid & 63, wv = tid >> 6;
  int lsub = lane >> 3, lchk = lane & 7;
  int co = (lchk ^ lsub) * 8;
  const u16* abase = act + (size_t)(row0l + wv * 32 + lsub) * I_DIM + co;
  const u16* bbase = D + (size_t)(col0 + wv * 16 + lsub) * I_DIM + lchk * 8;
  int ldstA = (wv * 32 + lsub) * 64 + lchk * 8;
  int ldstB = (wv * 16 + lsub) * 64 + lchk * 8;

  f32x4 acc[4][4];
#pragma unroll
  for (int m = 0; m < 4; m++)
#pragma unroll
    for (int n = 0; n < 4; n++) {
      f32x4 z = {0.f, 0.f, 0.f, 0.f};
      acc[m][n] = z;
    }
  int lr = lane & 15, lq = lane >> 4;
  int wr = wv >> 1, wc = wv & 1;           // wave tile: 64 rows x 64 cols

  auto stage = [&](int kt, int slot) {
    int kk = kt * BK;
#pragma unroll
    for (int j = 0; j < 4; j++)
      dma16(abase + (size_t)j * (8 * I_DIM) + kk, &As[slot][ldstA + j * 512]);
#pragma unroll
    for (int j = 0; j < 2; j++)
      dma16(bbase + (size_t)j * (8 * I_DIM) + kk, &Bs[slot][ldstB + j * 512]);
  };

  stage(0, 0);
  stage(1, 1);
  WAITVM(6);
  BAR();
  for (int kt = 0; kt < I_DIM / BK; ++kt) {
    const u16* Ab = As[kt & 1];
    const u16* Bb = Bs[kt & 1];
    __builtin_amdgcn_s_setprio(1);
#pragma unroll
    for (int s = 0; s < 2; ++s) {
      int csh = ((s * 4 + lq) ^ (lr & 7)) * 8;
      short8 bfr[4], afr[4];
#pragma unroll
      for (int n = 0; n < 4; n++)
        bfr[n] = *(const short8*)&Bb[(wc * 64 + n * 16 + lr) * 64 + csh];
#pragma unroll
      for (int m = 0; m < 4; m++)
        afr[m] = *(const short8*)&Ab[(wr * 64 + m * 16 + lr) * 64 + csh];
#pragma unroll
      for (int m = 0; m < 4; m++)
#pragma unroll
        for (int n = 0; n < 4; n++)
          acc[m][n] = __builtin_amdgcn_mfma_f32_16x16x32_bf16(afr[m], bfr[n], acc[m][n], 0, 0, 0);
    }
    __builtin_amdgcn_s_setprio(0);
    BAR();
    if (kt + 2 < I_DIM / BK) { stage(kt + 2, kt & 1); WAITVM(6); }
    else { WAITVM(0); }
    BAR();
  }
  const int* perm = ctrl + CI_PERM;
  const float* rw = (const float*)(ctrl + CI_RW);
#pragma unroll
  for (int m = 0; m < 4; m++)
#pragma unroll
    for (int rg = 0; rg < 4; rg++) {
      int rgrow = row0 + wr * 64 + m * 16 + lq * 4 + rg;
      int tokn = perm[rgrow];
      if (tokn < 0) continue;              // padding row
      float w = rw[rgrow];
      float* obase = out + (size_t)tokn * C_DIM + col0 + wc * 64 + lr;
#pragma unroll
      for (int n = 0; n < 4; n++)
        atomicAdd(obase + n * 16, acc[m][n][rg] * w);
    }
}

extern "C" void kernel_launch(void* const* d_in, const int* in_sizes, int n_in,
                              void* d_out, int out_size, void* d_ws, size_t ws_size,
                              hipStream_t stream) {
  (void)in_sizes; (void)n_in; (void)out_size; (void)ws_size;
  const float* x     = (const float*)d_in[0];
  const float* wgate = (const float*)d_in[1];
  const float* ebias = (const float*)d_in[2];
  const float* wg    = (const float*)d_in[3];
  const float* wu    = (const float*)d_in[4];
  const float* wd    = (const float*)d_in[5];
  const float* swg   = (const float*)d_in[6];
  const float* swu   = (const float*)d_in[7];
  const float* swd   = (const float*)d_in[8];
  float* out = (float*)d_out;
  char* ws = (char*)d_ws;
  int* ctrl = (int*)ws;
  u16* xb  = (u16*)(ws + XB_OFF);
  u16* wgu = (u16*)(ws + WGU_OFF);
  u16* wdp = (u16*)(ws + WDP_OFF);
  u16* act = (u16*)(ws + ACT_OFF);

  hipMemsetAsync(ws, 0, 256, stream);                           // expert counts = 0
  hipMemsetAsync(ws + (size_t)CI_PERM * 4, 0xFF, 53248 * 4, stream);  // perm = -1
  hipMemsetAsync(d_out, 0, (size_t)N_TOK * C_DIM * 4, stream);  // out = 0 (atomic target)
  router_kernel<<<N_TOK / 16, 256, 0, stream>>>(x, wgate, ebias, ctrl, xb);
  tiles_kernel<<<1, 64, 0, stream>>>(ctrl);
  scatter_kernel<<<N_TOK / 256, 256, 0, stream>>>(ctrl);
  convert_kernel<<<17 * 96 + 17 * 24, 256, 0, stream>>>(wg, wu, wd, swg, swu, swd, wgu, wdp);
  for (int p = 0; p < 2; p++) {
    gemm1_kernel<<<dim3(PASS_T, 2 * I_DIM / 256), 512, 0, stream>>>(xb, wgu, act, ctrl, p * PASS_T);
    gemm2_kernel<<<dim3(PASS_T, C_DIM / 128), 512, 0, stream>>>(act, wdp, out, ctrl, p * PASS_T);
  }
}

// Round 2
// 1077.683 us; speedup vs baseline: 1.0487x; 1.0487x over previous
//
#include <hip/hip_runtime.h>

typedef unsigned short u16;
typedef unsigned int u32;
typedef __attribute__((ext_vector_type(4))) float f32x4;
typedef __attribute__((ext_vector_type(8))) short short8;
typedef __attribute__((ext_vector_type(4))) u16 u16x4;
typedef __attribute__((ext_vector_type(8))) u16 u16x8;

#define N_TOK 16384
#define C_DIM 768
#define I_DIM 1536
#define N_EXP 16
#define TM 256          // row-tile (padding granularity)
#define NT1 12          // C_DIM/64 K-tiles in gemm1
#define NT2 24          // I_DIM/64 K-tiles in gemm2
#define MAXT 208        // worst-case tiles: <=144 routed + 64 shared
#define PASS_T 104      // tiles per pass (two passes)

// ctrl region int offsets (first 1MB of ws)
#define CI_COUNTS 0
#define CI_STARTS 32
#define CI_NTILES 64
#define CI_TILE_E 128        // [208]
#define CI_ESLOT 2048        // [N][2] packed (e<<24)|slot
#define CI_TOKW 36864        // [N][2] float weights
#define CI_PERM 102400       // [53248] padded row -> token (-1 = padding)
#define CI_RW 155648         // [53248] float per-row combine weight

// ws layout (bytes)
#define XB_OFF  1048576u             // bf16 x: 16384*768*2 = 25,165,824
#define WGU_OFF 26214400u            // bf16 [17][2I][C] g/u 16-interleaved, PLAIN: 80,216,064
#define WDP_OFF 106430464u           // bf16 [17][C][I] PLAIN:    40,108,032
#define ACT_OFF 146538496u           // bf16 act half: 26624*1536*2 = 81,788,928

// raw barriers + counted vmem waits (never drain vmcnt to 0 in steady state)
#define BAR() asm volatile("s_barrier" ::: "memory")
// closing barrier: drain own ds_reads first so the slot is reusable chip-wide
#define BAR_LG() asm volatile("s_waitcnt lgkmcnt(0)\n\ts_barrier" ::: "memory")
#define WAITVM(N) asm volatile("s_waitcnt vmcnt(" #N ")" ::: "memory")

__device__ __forceinline__ u16 f2bf(float f) {
  u32 x = __float_as_uint(f);
  return (u16)((x + 0x7FFFu + ((x >> 16) & 1u)) >> 16);  // RNE
}
__device__ __forceinline__ float bf2f(u16 h) {
  return __uint_as_float(((u32)h) << 16);
}
__device__ __forceinline__ void dma16(const void* g, void* l) {
  __builtin_amdgcn_global_load_lds(
      (const __attribute__((address_space(1))) unsigned int*)g,
      (__attribute__((address_space(3))) unsigned int*)l, 16, 0, 0);
}

// ---------------- weight convert: fp32 [K][N] -> bf16 [N][K] PLAIN rows.
// wgu: per expert a single [2I][C] matrix whose rows interleave g/u at 16-col
// granularity: combined row ng -> block b=ng>>5, gu=(ng>>4)&1, src col b*16+(ng&15).
__global__ void convert_kernel(const float* __restrict__ wg, const float* __restrict__ wu,
                               const float* __restrict__ wd, const float* __restrict__ swg,
                               const float* __restrict__ swu, const float* __restrict__ swd,
                               u16* __restrict__ wgu, u16* __restrict__ wdp) {
  int bid = blockIdx.x;
  int tid = threadIdx.x, lane = tid & 63, wv = tid >> 6;
  int lsub = lane >> 3, lchk = lane & 7;
  if (bid < 17 * 96) {                     // combined g/u part: 17 experts x 3072 rows
    int e = bid / 96, nb = bid % 96;
    int ng = nb * 32 + wv * 8 + lsub;      // combined dst row 0..3071
    int gu = (ng >> 4) & 1;
    int scol = ((ng >> 5) << 4) | (ng & 15);
    const float* src = (e < N_EXP) ? ((gu ? wu : wg) + (size_t)e * C_DIM * I_DIM)
                                   : (gu ? swu : swg);
    u16* drow = wgu + ((size_t)e * (2 * I_DIM) + ng) * C_DIM;
    const float* s0 = src + scol;
    for (int k0 = 0; k0 < C_DIM; k0 += 64) {
      u16x8 o;
#pragma unroll
      for (int j = 0; j < 8; j++) o[j] = f2bf(s0[(size_t)(k0 + lchk * 8 + j) * I_DIM]);
      *(u16x8*)&drow[k0 + lchk * 8] = o;
    }
  } else {                                 // wd part: [I][C] -> [C][I]
    int b2 = bid - 17 * 96;
    int e = b2 / 24, nb = b2 % 24;
    const float* src = (e < N_EXP) ? (wd + (size_t)e * I_DIM * C_DIM) : swd;
    u16* dst = wdp + (size_t)e * (I_DIM * C_DIM);
    int ng = nb * 32 + wv * 8 + lsub;
    const float* s0 = src + ng;
    u16* drow = dst + (size_t)ng * I_DIM;
    for (int k0 = 0; k0 < I_DIM; k0 += 64) {
      u16x8 o;
#pragma unroll
      for (int j = 0; j < 8; j++) o[j] = f2bf(s0[(size_t)(k0 + lchk * 8 + j) * C_DIM]);
      *(u16x8*)&drow[k0 + lchk * 8] = o;
    }
  }
}

// ---------------- router: fp32 logits, top-2, weights, counts; also casts x->bf16
__global__ void router_kernel(const float* __restrict__ x, const float* __restrict__ wgate,
                              const float* __restrict__ ebias, int* __restrict__ ctrl,
                              u16* __restrict__ xb) {
  __shared__ float xs[16 * 772];
  __shared__ float wgsT[16 * 772];      // transposed [e][c]
  __shared__ float lg[16 * 16];
  int tid = threadIdx.x;
  int tok0 = blockIdx.x * 16;
  const float4* xsrc = (const float4*)(x + (size_t)tok0 * C_DIM);
  const float4* wsrc = (const float4*)wgate;
#pragma unroll
  for (int j = 0; j < 12; j++) {
    int q = tid + j * 256;              // float4 unit, 0..3071
    float4 v = xsrc[q];
    int tk = q / 192;
    int c4 = q - tk * 192;
    *(float4*)&xs[tk * 772 + c4 * 4] = v;
    u16x4 o; o.x = f2bf(v.x); o.y = f2bf(v.y); o.z = f2bf(v.z); o.w = f2bf(v.w);
    *(u16x4*)(xb + (size_t)tok0 * C_DIM + (size_t)q * 4) = o;   // fused x->bf16 cast
    float4 w = wsrc[q];
    int c = q >> 2, e0 = (q & 3) * 4;
    wgsT[(e0 + 0) * 772 + c] = w.x;
    wgsT[(e0 + 1) * 772 + c] = w.y;
    wgsT[(e0 + 2) * 772 + c] = w.z;
    wgsT[(e0 + 3) * 772 + c] = w.w;
  }
  __syncthreads();
  int tk = tid >> 4, e = tid & 15;
  float acc = ebias[e];
  const float4* xr = (const float4*)&xs[tk * 772];
  const float4* wr = (const float4*)&wgsT[e * 772];
#pragma unroll 4
  for (int c4 = 0; c4 < 192; c4++) {
    float4 xv = xr[c4], wv = wr[c4];
    acc = fmaf(xv.x, wv.x, fmaf(xv.y, wv.y, fmaf(xv.z, wv.z, fmaf(xv.w, wv.w, acc))));
  }
  lg[tk * 16 + e] = acc;
  __syncthreads();
  if (tid < 16) {
    int n = tok0 + tid;
    float l0 = -1e30f, l1 = -1e30f; int i0 = 0, i1 = 0;
#pragma unroll
    for (int j = 0; j < 16; j++) {
      float l = lg[tid * 16 + j];
      if (l > l0) { l1 = l0; i1 = i0; l0 = l; i0 = j; }
      else if (l > l1) { l1 = l; i1 = j; }
    }
    float e1 = __expf(l1 - l0);
    float inv = 1.f / (1.f + e1);
    int s0 = atomicAdd(&ctrl[CI_COUNTS + i0], 1);
    int s1 = atomicAdd(&ctrl[CI_COUNTS + i1], 1);
    ctrl[CI_ESLOT + 2 * n]     = (i0 << 24) | s0;
    ctrl[CI_ESLOT + 2 * n + 1] = (i1 << 24) | s1;
    float* tw = (float*)(ctrl + CI_TOKW);
    tw[2 * n] = inv; tw[2 * n + 1] = e1 * inv;
  }
}

// ---------------- segment starts (padded to 256) + tile->expert map; shared = expert 16
__global__ void tiles_kernel(int* __restrict__ ctrl) {
  if (threadIdx.x != 0) return;
  int cnt[17];
#pragma unroll
  for (int e = 0; e < 16; e++) cnt[e] = ctrl[CI_COUNTS + e];
  cnt[16] = N_TOK;
  ctrl[CI_COUNTS + 16] = N_TOK;
  int cur = 0, T = 0;
  for (int e = 0; e <= 16; e++) {
    ctrl[CI_STARTS + e] = cur;
    int nt = (cnt[e] + TM - 1) >> 8;
    for (int i = 0; i < nt; i++) ctrl[CI_TILE_E + T++] = e;
    cur += nt << 8;
  }
  ctrl[CI_NTILES] = T;
}

// ---------------- scatter: fill perm[row]->token and per-row combine weight
__global__ void scatter_kernel(int* __restrict__ ctrl) {
  int n = blockIdx.x * 256 + threadIdx.x;
  const float* tw = (const float*)(ctrl + CI_TOKW);
  float* rw = (float*)(ctrl + CI_RW);
#pragma unroll
  for (int k = 0; k < 2; k++) {
    int es = ctrl[CI_ESLOT + 2 * n + k];
    int e = es >> 24;
    int slot = es & 0xFFFFFF;
    int row = ctrl[CI_STARTS + e] + slot;
    ctrl[CI_PERM + row] = n;
    rw[row] = tw[2 * n + k];
  }
  int srow = ctrl[CI_STARTS + 16] + n;     // shared expert row
  ctrl[CI_PERM + srow] = n;
  rw[srow] = 1.0f;
}

// ---------------- GEMM1: 256x256 combined tile, 8 waves, 8-phase fine pipeline.
// LDS ring: [2 dbuf][2 khalf] per matrix; each half = 256 rows x 32 k (plain rows
// of 32 u16, chunk-XOR swizzle applied via per-lane SOURCE addr + read offset).
// Per K-tile t (slot s=t&1), 4 phases:
//  p1: rdB(kh0)+rdA(g0,kh0); stage A[t+1]k1;             BAR; 16 MFMA; BAR_LG
//  p2: rdA(g1,kh0);          stage B[t+1]k1; vmcnt(8);   BAR; 16 MFMA; BAR_LG
//  p3: rdB(kh1)+rdA(g0,kh1); stage A[t+2]k0;             BAR; 16 MFMA; BAR_LG
//  p4: rdA(g1,kh1);          stage B[t+2]k0; vmcnt(8);   BAR; 16 MFMA; BAR_LG
// Stage-into-slot is always issued after the BAR_LG closing its last reader;
// vmcnt(8) leaves exactly the 4 newest half-stages in flight across barriers.
__global__ __launch_bounds__(512, 2)
void gemm1_kernel(const u16* __restrict__ xb, const u16* __restrict__ wgu,
                  u16* __restrict__ act, const int* __restrict__ ctrl, int tile0) {
  __shared__ u16 As[2][2][8192];
  __shared__ u16 Bs[2][2][8192];
  int tt = tile0 + blockIdx.x;
  if (tt >= ctrl[CI_NTILES]) return;
  int e = ctrl[CI_TILE_E + tt];
  int row0 = tt << 8;                      // global padded row base
  int row0l = blockIdx.x << 8;             // pass-local row base (act index)
  int col0c = blockIdx.y << 8;             // combined col base
  int seg = ctrl[CI_STARTS + e];
  bool sh = (e == N_EXP);
  const u16* W = wgu + (size_t)e * (2 * I_DIM * C_DIM);
  int rlim = sh ? 0x7fffffff : (seg + ctrl[CI_COUNTS + e]);
  const int* perm = ctrl + CI_PERM;
  int tid = threadIdx.x, lane = tid & 63, wv = tid >> 6;
  int lr = lane & 15, lq = lane >> 4;
  int kcl = (lane & 3) ^ ((lane >> 2) & 3);   // source k-chunk for this lane's dest slot
  // staging source pointers: lane covers rows (wv*16 + lane/4) and +128
  const u16 *aS0, *aS1, *bS0, *bS1;
  {
    int r0 = row0 + wv * 16 + (lane >> 2);
    int r1 = r0 + 128;
    int t0 = sh ? (r0 - seg) : ((r0 < rlim) ? perm[r0] : 0);
    int t1 = sh ? (r1 - seg) : ((r1 < rlim) ? perm[r1] : 0);
    aS0 = xb + (size_t)t0 * C_DIM + kcl * 8;
    aS1 = xb + (size_t)t1 * C_DIM + kcl * 8;
    int cb = col0c + wv * 16 + (lane >> 2);
    bS0 = W + (size_t)cb * C_DIM + kcl * 8;
    bS1 = W + (size_t)(cb + 128) * C_DIM + kcl * 8;
  }
  int dofs = tid * 8;                      // u16: = wave_base + lane*16B (HW dest rule)

  auto stA = [&](int kt, int kh) {
    u16* d = &As[kt & 1][kh][dofs];
    int ko = kt * 64 + kh * 32;
    dma16(aS0 + ko, d);
    dma16(aS1 + ko, d + 4096);
  };
  auto stB = [&](int kt, int kh) {
    u16* d = &Bs[kt & 1][kh][dofs];
    int ko = kt * 64 + kh * 32;
    dma16(bS0 + ko, d);
    dma16(bS1 + ko, d + 4096);
  };

  f32x4 acc[8][4];
#pragma unroll
  for (int m = 0; m < 8; m++)
#pragma unroll
    for (int n = 0; n < 4; n++) {
      f32x4 z = {0.f, 0.f, 0.f, 0.f};
      acc[m][n] = z;
    }
  int wr = wv >> 2, wc = wv & 3;           // wave tile: 128 rows x 64 combined cols
  short8 afr[4], bfr[4];

  auto rdB = [&](int s, int kh) {
#pragma unroll
    for (int n = 0; n < 4; n++) {
      int i = wc * 64 + n * 16 + lr;
      bfr[n] = *(const short8*)&Bs[s][kh][i * 32 + ((lq ^ (i & 3)) * 8)];
    }
  };
  auto rdA = [&](int s, int kh, int g) {
#pragma unroll
    for (int m = 0; m < 4; m++) {
      int r = wr * 128 + g * 64 + m * 16 + lr;
      afr[m] = *(const short8*)&As[s][kh][r * 32 + ((lq ^ (r & 3)) * 8)];
    }
  };
  auto mm = [&](int g) {
    __builtin_amdgcn_s_setprio(1);
#pragma unroll
    for (int m = 0; m < 4; m++)
#pragma unroll
      for (int n = 0; n < 4; n++)
        acc[g * 4 + m][n] = __builtin_amdgcn_mfma_f32_16x16x32_bf16(
            afr[m], bfr[n], acc[g * 4 + m][n], 0, 0, 0);
    __builtin_amdgcn_s_setprio(0);
  };

  // prologue: tile0 both halves + tile1 k0 (12 loads); wait first K-half pair landed
  stA(0, 0); stB(0, 0); stA(0, 1); stB(0, 1); stA(1, 0); stB(1, 0);
  WAITVM(8);
  BAR();
  for (int kt = 0; kt < NT1; ++kt) {
    int s = kt & 1;
    // phase 1
    rdB(s, 0); rdA(s, 0, 0);
    if (kt + 1 < NT1) stA(kt + 1, 1);
    BAR(); mm(0); BAR_LG();
    // phase 2
    rdA(s, 0, 1);
    if (kt + 1 < NT1) stB(kt + 1, 1);
    if (kt == NT1 - 1) { WAITVM(0); } else { WAITVM(8); }
    BAR(); mm(1); BAR_LG();
    // phase 3
    rdB(s, 1); rdA(s, 1, 0);
    if (kt + 2 < NT1) stA(kt + 2, 0);
    BAR(); mm(0); BAR_LG();
    // phase 4
    rdA(s, 1, 1);
    if (kt + 2 < NT1) stB(kt + 2, 0);
    if (kt < NT1 - 2) { WAITVM(8); } else if (kt == NT1 - 2) { WAITVM(4); }
    BAR(); mm(1); BAR_LG();
  }
  // epilogue: pair g (n even) with u (n odd), silu, store bf16
  int cbase = (blockIdx.y << 7) + wc * 32;  // act col base for this wave
#pragma unroll
  for (int mi = 0; mi < 8; mi++)
#pragma unroll
    for (int np = 0; np < 2; np++)
#pragma unroll
      for (int rg = 0; rg < 4; rg++) {
        float g = acc[mi][2 * np][rg];
        float h = acc[mi][2 * np + 1][rg];
        float a = g * (1.f / (1.f + __expf(-g))) * h;
        int r_loc = wr * 128 + mi * 16 + lq * 4 + rg;
        act[(size_t)(row0l + r_loc) * I_DIM + cbase + np * 16 + lr] = f2bf(a);
      }
}

// ---------------- GEMM2: 128x128 tile, 4 waves, 2-phase-per-K-tile fine pipeline,
// 2 blocks/CU. out += rowweight * (act @ Wd), fp32 atomics.
__global__ __launch_bounds__(256, 2)
void gemm2_kernel(const u16* __restrict__ act, const u16* __restrict__ wdp,
                  float* __restrict__ out, const int* __restrict__ ctrl, int tile0) {
  __shared__ u16 As[2][2][4096];
  __shared__ u16 Bs[2][2][4096];
  int bx = blockIdx.x;
  int tt = tile0 + (bx >> 1);
  if (tt >= ctrl[CI_NTILES]) return;
  int e = ctrl[CI_TILE_E + tt];
  int sub = bx & 1;
  int row0g = (tt << 8) + (sub << 7);      // global padded row base
  int row0l = bx << 7;                     // pass-local act row base
  int col0 = blockIdx.y << 7;              // over C
  const u16* D = wdp + (size_t)e * (I_DIM * C_DIM);
  int tid = threadIdx.x, lane = tid & 63, wv = tid >> 6;
  int lr = lane & 15, lq = lane >> 4;
  int kcl = (tid & 3) ^ ((tid >> 2) & 3);
  const u16 *aS0, *aS1, *bS0, *bS1;
  {
    int r0 = tid >> 2;                     // rows r0 and r0+64
    aS0 = act + (size_t)(row0l + r0) * I_DIM + kcl * 8;
    aS1 = act + (size_t)(row0l + r0 + 64) * I_DIM + kcl * 8;
    bS0 = D + (size_t)(col0 + r0) * I_DIM + kcl * 8;
    bS1 = D + (size_t)(col0 + r0 + 64) * I_DIM + kcl * 8;
  }
  int dofs = tid * 8;

  auto stA = [&](int kt, int kh) {
    u16* d = &As[kt & 1][kh][dofs];
    int ko = kt * 64 + kh * 32;
    dma16(aS0 + ko, d);
    dma16(aS1 + ko, d + 2048);
  };
  auto stB = [&](int kt, int kh) {
    u16* d = &Bs[kt & 1][kh][dofs];
    int ko = kt * 64 + kh * 32;
    dma16(bS0 + ko, d);
    dma16(bS1 + ko, d + 2048);
  };

  f32x4 acc[4][4];
#pragma unroll
  for (int m = 0; m < 4; m++)
#pragma unroll
    for (int n = 0; n < 4; n++) {
      f32x4 z = {0.f, 0.f, 0.f, 0.f};
      acc[m][n] = z;
    }
  int wr = wv >> 1, wc = wv & 1;           // wave tile: 64 rows x 64 cols
  short8 afr[4], bfr[4];

  auto rdB = [&](int s, int kh) {
#pragma unroll
    for (int n = 0; n < 4; n++) {
      int i = wc * 64 + n * 16 + lr;
      bfr[n] = *(const short8*)&Bs[s][kh][i * 32 + ((lq ^ (i & 3)) * 8)];
    }
  };
  auto rdA = [&](int s, int kh) {
#pragma unroll
    for (int m = 0; m < 4; m++) {
      int r = wr * 64 + m * 16 + lr;
      afr[m] = *(const short8*)&As[s][kh][r * 32 + ((lq ^ (r & 3)) * 8)];
    }
  };
  auto mm = [&]() {
    __builtin_amdgcn_s_setprio(1);
#pragma unroll
    for (int m = 0; m < 4; m++)
#pragma unroll
      for (int n = 0; n < 4; n++)
        acc[m][n] = __builtin_amdgcn_mfma_f32_16x16x32_bf16(afr[m], bfr[n], acc[m][n], 0, 0, 0);
    __builtin_amdgcn_s_setprio(0);
  };

  stA(0, 0); stB(0, 0); stA(0, 1); stB(0, 1); stA(1, 0); stB(1, 0);
  WAITVM(8);
  BAR();
  for (int kt = 0; kt < NT2; ++kt) {
    int s = kt & 1;
    // phase 1 (kh0)
    rdB(s, 0); rdA(s, 0);
    if (kt + 1 < NT2) { stA(kt + 1, 1); stB(kt + 1, 1); }
    if (kt == NT2 - 1) { WAITVM(0); } else { WAITVM(8); }
    BAR(); mm(); BAR_LG();
    // phase 2 (kh1)
    rdB(s, 1); rdA(s, 1);
    if (kt + 2 < NT2) { stA(kt + 2, 0); stB(kt + 2, 0); }
    if (kt < NT2 - 2) { WAITVM(8); } else if (kt == NT2 - 2) { WAITVM(4); }
    BAR(); mm(); BAR_LG();
  }
  const int* perm = ctrl + CI_PERM;
  const float* rw = (const float*)(ctrl + CI_RW);
#pragma unroll
  for (int m = 0; m < 4; m++)
#pragma unroll
    for (int rg = 0; rg < 4; rg++) {
      int rgrow = row0g + wr * 64 + m * 16 + lq * 4 + rg;
      int tokn = perm[rgrow];
      if (tokn < 0) continue;              // padding row
      float w = rw[rgrow];
      float* obase = out + (size_t)tokn * C_DIM + col0 + wc * 64 + lr;
#pragma unroll
      for (int n = 0; n < 4; n++)
        atomicAdd(obase + n * 16, acc[m][n][rg] * w);
    }
}

extern "C" void kernel_launch(void* const* d_in, const int* in_sizes, int n_in,
                              void* d_out, int out_size, void* d_ws, size_t ws_size,
                              hipStream_t stream) {
  (void)in_sizes; (void)n_in; (void)out_size; (void)ws_size;
  const float* x     = (const float*)d_in[0];
  const float* wgate = (const float*)d_in[1];
  const float* ebias = (const float*)d_in[2];
  const float* wg    = (const float*)d_in[3];
  const float* wu    = (const float*)d_in[4];
  const float* wd    = (const float*)d_in[5];
  const float* swg   = (const float*)d_in[6];
  const float* swu   = (const float*)d_in[7];
  const float* swd   = (const float*)d_in[8];
  float* out = (float*)d_out;
  char* ws = (char*)d_ws;
  int* ctrl = (int*)ws;
  u16* xb  = (u16*)(ws + XB_OFF);
  u16* wgu = (u16*)(ws + WGU_OFF);
  u16* wdp = (u16*)(ws + WDP_OFF);
  u16* act = (u16*)(ws + ACT_OFF);

  hipMemsetAsync(ws, 0, 256, stream);                           // expert counts = 0
  hipMemsetAsync(ws + (size_t)CI_PERM * 4, 0xFF, 53248 * 4, stream);  // perm = -1
  hipMemsetAsync(d_out, 0, (size_t)N_TOK * C_DIM * 4, stream);  // out = 0 (atomic target)
  router_kernel<<<N_TOK / 16, 256, 0, stream>>>(x, wgate, ebias, ctrl, xb);
  tiles_kernel<<<1, 64, 0, stream>>>(ctrl);
  scatter_kernel<<<N_TOK / 256, 256, 0, stream>>>(ctrl);
  convert_kernel<<<17 * 96 + 17 * 24, 256, 0, stream>>>(wg, wu, wd, swg, swu, swd, wgu, wdp);
  for (int p = 0; p < 2; p++) {
    gemm1_kernel<<<dim3(PASS_T, 2 * I_DIM / 256), 512, 0, stream>>>(xb, wgu, act, ctrl, p * PASS_T);
    gemm2_kernel<<<dim3(2 * PASS_T, C_DIM / 128), 256, 0, stream>>>(act, wdp, out, ctrl, p * PASS_T);
  }
}